// Round 3
// baseline (688.168 us; speedup 1.0000x reference)
//
#include <hip/hip_runtime.h>
#include <hip/hip_bf16.h>

#define NUSERS 100000
#define NITEMS 50000
#define NNODES 150000
#define EMB 64
#define NLAYERS 3
#define NEDGES 2400000
#define SCAN_ITEMS 1024
#define NSCAN_BLOCKS ((NNODES + SCAN_ITEMS - 1) / SCAN_ITEMS)   // 147
#define NBUCK 8   // XCD count; bucket = blockIdx&7 ~ round-robin XCD mapping

typedef __attribute__((ext_vector_type(8))) short short8;
typedef __attribute__((ext_vector_type(4))) float float4v;

__device__ __forceinline__ float bf2f(unsigned short u) {
    return __uint_as_float((unsigned int)u << 16);
}
__device__ __forceinline__ unsigned short f2bf(float f) {
    unsigned int x = __float_as_uint(f);
    return (unsigned short)((x + 0x7FFFu + ((x >> 16) & 1u)) >> 16);   // RNE
}
__device__ __forceinline__ float bfl(unsigned int u) { return __uint_as_float(u << 16); }
__device__ __forceinline__ float bfh(unsigned int u) { return __uint_as_float(u & 0xffff0000u); }

// ---------- CSR build ----------
// r0 measured: single-copy hist_rank = 101us (2.4M returning atomics, ~21 CU-cyc
// each; WRITE_SIZE 86MB write-through). Theory: 7/8 of atomics cross XCD fabric.
// This version privatizes deg[] 8-ways by blockIdx&7 (~XCD-local L2 atomics);
// bucket_prefix converts bucket-local ranks to global CSR slots.

__global__ __launch_bounds__(256) void hist8_kernel(
    const int* __restrict__ rows, int* __restrict__ deg8, int* __restrict__ rank)
{
    int e = blockIdx.x * 256 + threadIdx.x;
    if (e >= NEDGES) return;
    int b = blockIdx.x & (NBUCK - 1);
    rank[e] = atomicAdd(&deg8[b * NNODES + rows[e]], 1);
}

// per-row exclusive prefix over the 8 buckets (in place); total -> deg_tot
__global__ __launch_bounds__(256) void bucket_prefix_kernel(
    int* __restrict__ deg8, int* __restrict__ deg_tot)
{
    int i = blockIdx.x * 256 + threadIdx.x;
    if (i >= NNODES) return;
    int s = 0;
    #pragma unroll
    for (int b = 0; b < NBUCK; ++b) {
        int v = deg8[b * NNODES + i];
        deg8[b * NNODES + i] = s;
        s += v;
    }
    deg_tot[i] = s;
}

__global__ __launch_bounds__(256) void block_sum_kernel(
    const int* __restrict__ deg, int* __restrict__ bsum)
{
    __shared__ int lds[256];
    int t = threadIdx.x;
    int base = blockIdx.x * SCAN_ITEMS + t * 4;
    int s = 0;
    #pragma unroll
    for (int k = 0; k < 4; ++k) {
        int idx = base + k;
        s += (idx < NNODES) ? deg[idx] : 0;
    }
    lds[t] = s; __syncthreads();
    for (int off = 128; off; off >>= 1) {
        if (t < off) lds[t] += lds[t + off];
        __syncthreads();
    }
    if (t == 0) bsum[blockIdx.x] = lds[0];
}

__global__ __launch_bounds__(256) void scan_partials_kernel(
    const int* __restrict__ bsum, int* __restrict__ bscan, int* __restrict__ rowptr)
{
    __shared__ int lds[256];
    int t = threadIdx.x;
    int v = (t < NSCAN_BLOCKS) ? bsum[t] : 0;
    lds[t] = v; __syncthreads();
    for (int off = 1; off < 256; off <<= 1) {
        int add = (t >= off) ? lds[t - off] : 0;
        __syncthreads();
        lds[t] += add;
        __syncthreads();
    }
    if (t < NSCAN_BLOCKS) bscan[t] = lds[t] - v;
    if (t == 0) rowptr[NNODES] = NEDGES;
}

__global__ __launch_bounds__(256) void block_scan_kernel(
    const int* __restrict__ deg, const int* __restrict__ bscan,
    int* __restrict__ rowptr)
{
    __shared__ int lds[256];
    int t = threadIdx.x;
    int base = blockIdx.x * SCAN_ITEMS + t * 4;
    int d[4]; int s = 0;
    #pragma unroll
    for (int k = 0; k < 4; ++k) {
        int idx = base + k;
        d[k] = (idx < NNODES) ? deg[idx] : 0;
        s += d[k];
    }
    lds[t] = s; __syncthreads();
    int v = s;
    for (int off = 1; off < 256; off <<= 1) {
        int add = (t >= off) ? lds[t - off] : 0;
        __syncthreads();
        lds[t] += add;
        __syncthreads();
    }
    int ex = lds[t] - v + bscan[blockIdx.x];
    #pragma unroll
    for (int k = 0; k < 4; ++k) {
        int idx = base + k;
        if (idx < NNODES) { rowptr[idx] = ex; ex += d[k]; }
    }
}

// pos = rowptr[row] + bucket_prefix[b][row] + bucket_local_rank
// (same grid/block mapping as hist8 so b matches per edge)
__global__ __launch_bounds__(256) void scatter8_kernel(
    const int* __restrict__ rows, const int* __restrict__ cols,
    const float* __restrict__ vals, const int* __restrict__ rank,
    const int* __restrict__ rowptr, const int* __restrict__ pre8,
    int2* __restrict__ edges)
{
    int e = blockIdx.x * 256 + threadIdx.x;
    if (e >= NEDGES) return;
    int b = blockIdx.x & (NBUCK - 1);
    int row = rows[e];
    int pos = rowptr[row] + pre8[b * NNODES + row] + rank[e];
    edges[pos] = make_int2(cols[e], __float_as_int(vals[e]));
}

// ---------- weight fp32 -> bf16, TRANSPOSED to [layer][n][k] (once) ----------
__global__ __launch_bounds__(256) void wconv_kernel(
    const float* __restrict__ gw, const float* __restrict__ bw,
    unsigned short* __restrict__ wg_bf, unsigned short* __restrict__ wb_bf)
{
    int i = blockIdx.x * 256 + threadIdx.x;
    if (i >= NLAYERS * EMB * EMB) return;
    int l = i >> 12;
    int k = (i >> 6) & 63;
    int n = i & 63;
    int o = (l << 12) | (n << 6) | k;   // [l][n][k]
    wg_bf[o] = f2bf(gw[i]);
    wb_bf[o] = f2bf(bw[i]);
}

// ---------- ego init (bf16) + output cols 0..63 (fp32) ----------
__global__ __launch_bounds__(256) void init_kernel(
    const float* __restrict__ ue, const float* __restrict__ ie,
    unsigned short* __restrict__ ego_bf, float* __restrict__ out)
{
    int i = blockIdx.x * 256 + threadIdx.x;   // float4 index over NNODES*16
    if (i >= NNODES * 16) return;
    int n = i >> 4, q = i & 15;
    float4 v = (n < NUSERS) ? ((const float4*)ue)[i]
                            : ((const float4*)ie)[i - NUSERS * 16];
    *(float4*)(out + (size_t)n * 256 + q * 4) = v;
    ushort4 b;
    b.x = f2bf(v.x); b.y = f2bf(v.y); b.z = f2bf(v.z); b.w = f2bf(v.w);
    *(ushort4*)(ego_bf + (size_t)n * EMB + q * 4) = b;
}

// ---------- fused layer: SpMM (pull, into LDS) + MFMA dense + norm ----------
// Block = 256 threads, 64 rows. Phase 1: 16-lane group g pulls rows base+k*16+g
// (k=0..3), lane cp owns cols cp*4..cp*4+3 (uint2 gather = 128B/line per group),
// 4 edges in flight. side -> LDS [4][16][72] (pad 72 kills 128B-stride bank
// conflict). Phase 2: wave w = one 16-row MFMA tile. ego double-buffered across
// layers (in!=out) so no cross-block race. Saves 38.4MB/layer side round-trip.
__global__ __launch_bounds__(256) void layer_fused(
    const int* __restrict__ rowptr, const int2* __restrict__ edges,
    const unsigned short* __restrict__ ego_in, unsigned short* __restrict__ ego_out,
    const unsigned short* __restrict__ wg_bf, const unsigned short* __restrict__ wb_bf,
    const float* __restrict__ gb, const float* __restrict__ bb,
    float* __restrict__ out, int out_col0)
{
    __shared__ unsigned short lds_side[4][16][72];   // 9216 B

    const int t    = threadIdx.x;
    const int cp   = t & 15;
    const int g    = t >> 4;                 // 0..15
    const int base = (int)blockIdx.x * 64;

    // ---- phase 1: pull-SpMM, 4 rows per group ----
    #pragma unroll
    for (int k = 0; k < 4; ++k) {
        int r = base + k * 16 + g;
        if (r < NNODES) {
            const int s = rowptr[r], e = rowptr[r + 1];
            float a0 = 0.f, a1 = 0.f, a2 = 0.f, a3 = 0.f;
            float b0 = 0.f, b1 = 0.f, b2 = 0.f, b3 = 0.f;
            int i = s;
            for (; i + 4 <= e; i += 4) {            // 4 edges / 8 loads in flight
                int2 e0 = edges[i],     e1 = edges[i + 1];
                int2 e2 = edges[i + 2], e3 = edges[i + 3];
                uint2 u0 = *(const uint2*)(ego_in + (size_t)e0.x * EMB + cp * 4);
                uint2 u1 = *(const uint2*)(ego_in + (size_t)e1.x * EMB + cp * 4);
                uint2 u2 = *(const uint2*)(ego_in + (size_t)e2.x * EMB + cp * 4);
                uint2 u3 = *(const uint2*)(ego_in + (size_t)e3.x * EMB + cp * 4);
                float v0 = __int_as_float(e0.y), v1 = __int_as_float(e1.y);
                float v2 = __int_as_float(e2.y), v3 = __int_as_float(e3.y);
                a0 += v0 * bfl(u0.x); a1 += v0 * bfh(u0.x);
                a2 += v0 * bfl(u0.y); a3 += v0 * bfh(u0.y);
                b0 += v1 * bfl(u1.x); b1 += v1 * bfh(u1.x);
                b2 += v1 * bfl(u1.y); b3 += v1 * bfh(u1.y);
                a0 += v2 * bfl(u2.x); a1 += v2 * bfh(u2.x);
                a2 += v2 * bfl(u2.y); a3 += v2 * bfh(u2.y);
                b0 += v3 * bfl(u3.x); b1 += v3 * bfh(u3.x);
                b2 += v3 * bfl(u3.y); b3 += v3 * bfh(u3.y);
            }
            for (; i < e; ++i) {
                int2 e0 = edges[i];
                float v0 = __int_as_float(e0.y);
                uint2 u0 = *(const uint2*)(ego_in + (size_t)e0.x * EMB + cp * 4);
                a0 += v0 * bfl(u0.x); a1 += v0 * bfh(u0.x);
                a2 += v0 * bfl(u0.y); a3 += v0 * bfh(u0.y);
            }
            a0 += b0; a1 += b1; a2 += b2; a3 += b3;
            ushort4 o;
            o.x = f2bf(a0); o.y = f2bf(a1); o.z = f2bf(a2); o.w = f2bf(a3);
            *(ushort4*)&lds_side[k][g][cp * 4] = o;
        }
    }
    __syncthreads();

    // ---- phase 2: wave w = tile (base + w*16 .. +15) ----
    const int lane = t & 63;
    const int w    = t >> 6;
    const int m    = lane & 15;     // A row / B,C col
    const int q    = lane >> 4;     // quad
    const int tb   = base + w * 16;
    if (tb >= NNODES) return;

    // B fragments (weights transposed [n][k]): contiguous short8 loads
    short8 bg[4][2], bbf[4][2];
    #pragma unroll
    for (int n0 = 0; n0 < 4; ++n0) {
        const int n = n0 * 16 + m;
        #pragma unroll
        for (int kh = 0; kh < 2; ++kh) {
            bg [n0][kh] = *(const short8*)(wg_bf + n * EMB + kh * 32 + q * 8);
            bbf[n0][kh] = *(const short8*)(wb_bf + n * EMB + kh * 32 + q * 8);
        }
    }
    float bgc[4], bbc[4];
    #pragma unroll
    for (int n0 = 0; n0 < 4; ++n0) { bgc[n0] = gb[n0 * 16 + m]; bbc[n0] = bb[n0 * 16 + m]; }

    // A fragments: side from LDS, ego_in from global (L2-hot)
    short8 as0 = *(const short8*)&lds_side[w][m][q * 8];
    short8 as1 = *(const short8*)&lds_side[w][m][q * 8 + 32];
    short8 ae0 = *(const short8*)(ego_in + (size_t)(tb + m) * EMB + q * 8);
    short8 ae1 = *(const short8*)(ego_in + (size_t)(tb + m) * EMB + q * 8 + 32);
    short8 ap0, ap1;
    #pragma unroll
    for (int jj = 0; jj < 8; ++jj) {
        ap0[jj] = (short)f2bf(bf2f((unsigned short)as0[jj]) * bf2f((unsigned short)ae0[jj]));
        ap1[jj] = (short)f2bf(bf2f((unsigned short)as1[jj]) * bf2f((unsigned short)ae1[jj]));
    }

    float4v c1[4], c2[4];
    #pragma unroll
    for (int n0 = 0; n0 < 4; ++n0) { c1[n0] = (float4v)0.f; c2[n0] = (float4v)0.f; }
    #pragma unroll
    for (int n0 = 0; n0 < 4; ++n0) {
        c1[n0] = __builtin_amdgcn_mfma_f32_16x16x32_bf16(as0, bg [n0][0], c1[n0], 0, 0, 0);
        c1[n0] = __builtin_amdgcn_mfma_f32_16x16x32_bf16(as1, bg [n0][1], c1[n0], 0, 0, 0);
        c2[n0] = __builtin_amdgcn_mfma_f32_16x16x32_bf16(ap0, bbf[n0][0], c2[n0], 0, 0, 0);
        c2[n0] = __builtin_amdgcn_mfma_f32_16x16x32_bf16(ap1, bbf[n0][1], c2[n0], 0, 0, 0);
    }

    // epilogue: bias + leaky + ego update + L2 norm
    float eg[4][4];          // [n0][reg]; row = tb + q*4 + reg, col = n0*16 + m
    float ss[4] = {0.f, 0.f, 0.f, 0.f};
    #pragma unroll
    for (int n0 = 0; n0 < 4; ++n0) {
        #pragma unroll
        for (int r = 0; r < 4; ++r) {
            float x1 = c1[n0][r] + bgc[n0];
            float x2 = c2[n0][r] + bbc[n0];
            float v1 = x1 > 0.f ? x1 : 0.01f * x1;
            float v2 = x2 > 0.f ? x2 : 0.01f * x2;
            float e = v1 + v2;
            eg[n0][r] = e;
            ss[r] += e * e;
        }
    }
    #pragma unroll
    for (int r = 0; r < 4; ++r) {
        float s = ss[r];
        s += __shfl_xor(s, 1, 64);
        s += __shfl_xor(s, 2, 64);
        s += __shfl_xor(s, 4, 64);
        s += __shfl_xor(s, 8, 64);
        ss[r] = 1.0f / fmaxf(sqrtf(s), 1e-12f);
    }
    #pragma unroll
    for (int r = 0; r < 4; ++r) {
        int row = tb + q * 4 + r;
        #pragma unroll
        for (int n0 = 0; n0 < 4; ++n0) {
            int col = n0 * 16 + m;
            ego_out[(size_t)row * EMB + col] = f2bf(eg[n0][r]);
            out[(size_t)row * 256 + out_col0 + col] = eg[n0][r] * ss[r];
        }
    }
}

extern "C" void kernel_launch(void* const* d_in, const int* in_sizes, int n_in,
                              void* d_out, int out_size, void* d_ws, size_t ws_size,
                              hipStream_t stream)
{
    const int*   rows = (const int*)  d_in[0];
    const int*   cols = (const int*)  d_in[1];
    const float* vals = (const float*)d_in[2];
    const float* ue   = (const float*)d_in[3];
    const float* ie   = (const float*)d_in[4];
    const float* gw   = (const float*)d_in[5];
    const float* gb   = (const float*)d_in[6];
    const float* bw   = (const float*)d_in[7];
    const float* bb   = (const float*)d_in[8];
    float* out = (float*)d_out;

    // ---- workspace layout (~58.3 MB) ----
    char* p = (char*)d_ws;
    unsigned short* ego0 = (unsigned short*)p;  p += (size_t)NNODES * EMB * 2;  // 19.2 MB
    unsigned short* ego1 = (unsigned short*)p;  p += (size_t)NNODES * EMB * 2;  // 19.2 MB
    int2*  edges  = (int2*)p;    p += (size_t)NEDGES * 8;                       // 19.2 MB
    int*   rowptr = (int*)p;     p += ((size_t)NNODES + 4) * 4;                 // 0.6 MB
    unsigned short* wg_bf = (unsigned short*)p;  p += (size_t)NLAYERS * EMB * EMB * 2;
    unsigned short* wb_bf = (unsigned short*)p;  p += (size_t)NLAYERS * EMB * EMB * 2;
    // build scratch aliased into ego1 (15.0 MB < 19.2 MB; ego1 first written by
    // layer-0 dense phase, after the build is complete)
    int* deg8    = (int*)ego1;                    // 8 x NNODES  (4.8 MB)
    int* rank    = deg8 + NBUCK * NNODES;         // NEDGES      (9.6 MB)
    int* deg_tot = rank + NEDGES;                 // NNODES      (0.6 MB)
    int* bsum    = deg_tot + NNODES;
    int* bscan   = bsum + 256;

    // ---- CSR build (XCD-privatized atomics) ----
    hipMemsetAsync(deg8, 0, (size_t)NBUCK * NNODES * 4, stream);
    hist8_kernel<<<(NEDGES + 255) / 256, 256, 0, stream>>>(rows, deg8, rank);
    bucket_prefix_kernel<<<(NNODES + 255) / 256, 256, 0, stream>>>(deg8, deg_tot);
    block_sum_kernel<<<NSCAN_BLOCKS, 256, 0, stream>>>(deg_tot, bsum);
    scan_partials_kernel<<<1, 256, 0, stream>>>(bsum, bscan, rowptr);
    block_scan_kernel<<<NSCAN_BLOCKS, 256, 0, stream>>>(deg_tot, bscan, rowptr);
    scatter8_kernel<<<(NEDGES + 255) / 256, 256, 0, stream>>>(
        rows, cols, vals, rank, rowptr, deg8, edges);

    wconv_kernel<<<(NLAYERS * EMB * EMB + 255) / 256, 256, 0, stream>>>(gw, bw, wg_bf, wb_bf);
    init_kernel<<<(NNODES * 16 + 255) / 256, 256, 0, stream>>>(ue, ie, ego0, out);

    for (int l = 0; l < NLAYERS; ++l) {
        const unsigned short* ein = (l & 1) ? ego1 : ego0;
        unsigned short*       eout = (l & 1) ? ego0 : ego1;
        layer_fused<<<(NNODES + 63) / 64, 256, 0, stream>>>(
            rowptr, edges, ein, eout,
            wg_bf + l * EMB * EMB, wb_bf + l * EMB * EMB,
            gb + l * EMB, bb + l * EMB,
            out, 64 * (l + 1));
    }
}

// Round 4
// 657.892 us; speedup vs baseline: 1.0460x; 1.0460x over previous
//
#include <hip/hip_runtime.h>
#include <hip/hip_bf16.h>

#define NUSERS 100000
#define NITEMS 50000
#define NNODES 150000
#define EMB 64
#define NLAYERS 3
#define NEDGES 2400000
#define SCAN_ITEMS 1024
#define NSCAN_BLOCKS ((NNODES + SCAN_ITEMS - 1) / SCAN_ITEMS)   // 147
#define NTILES (NNODES / 16)                                    // 9375

typedef __attribute__((ext_vector_type(8))) short short8;
typedef __attribute__((ext_vector_type(4))) float float4v;

__device__ __forceinline__ float bf2f(unsigned short u) {
    return __uint_as_float((unsigned int)u << 16);
}
__device__ __forceinline__ unsigned short f2bf(float f) {
    unsigned int x = __float_as_uint(f);
    return (unsigned short)((x + 0x7FFFu + ((x >> 16) & 1u)) >> 16);   // RNE
}
__device__ __forceinline__ float bfl(unsigned int u) { return __uint_as_float(u << 16); }
__device__ __forceinline__ float bfh(unsigned int u) { return __uint_as_float(u & 0xffff0000u); }

// ---------- CSR build (once; adjacency identical for all layers) ----------
// MEASURED HISTORY (do not re-try):
//  - r0: single-copy hist_rank = 101us (2.4M returning atomics). Atomic wall.
//  - r3: 8-way XCD-privatized hist (bucket=blockIdx&7) REGRESSED (+56us total).
//    Atomics execute at the ADDRESS-HOME L2 slice (memory-side, address-
//    interleaved), not the issuing XCD's L2 — issuer-side bucketing localizes
//    nothing and adds memset/prefix/scatter-gather overhead. Reverted.

__global__ __launch_bounds__(256) void hist_rank_kernel(
    const int* __restrict__ rows, int* __restrict__ deg, int* __restrict__ rank)
{
    int e = blockIdx.x * 256 + threadIdx.x;
    if (e >= NEDGES) return;
    rank[e] = atomicAdd(&deg[rows[e]], 1);
}

__global__ __launch_bounds__(256) void block_sum_kernel(
    const int* __restrict__ deg, int* __restrict__ bsum)
{
    __shared__ int lds[256];
    int t = threadIdx.x;
    int base = blockIdx.x * SCAN_ITEMS + t * 4;
    int s = 0;
    #pragma unroll
    for (int k = 0; k < 4; ++k) {
        int idx = base + k;
        s += (idx < NNODES) ? deg[idx] : 0;
    }
    lds[t] = s; __syncthreads();
    for (int off = 128; off; off >>= 1) {
        if (t < off) lds[t] += lds[t + off];
        __syncthreads();
    }
    if (t == 0) bsum[blockIdx.x] = lds[0];
}

__global__ __launch_bounds__(256) void scan_partials_kernel(
    const int* __restrict__ bsum, int* __restrict__ bscan, int* __restrict__ rowptr)
{
    __shared__ int lds[256];
    int t = threadIdx.x;
    int v = (t < NSCAN_BLOCKS) ? bsum[t] : 0;
    lds[t] = v; __syncthreads();
    for (int off = 1; off < 256; off <<= 1) {
        int add = (t >= off) ? lds[t - off] : 0;
        __syncthreads();
        lds[t] += add;
        __syncthreads();
    }
    if (t < NSCAN_BLOCKS) bscan[t] = lds[t] - v;
    if (t == 0) rowptr[NNODES] = NEDGES;
}

__global__ __launch_bounds__(256) void block_scan_kernel(
    const int* __restrict__ deg, const int* __restrict__ bscan,
    int* __restrict__ rowptr)
{
    __shared__ int lds[256];
    int t = threadIdx.x;
    int base = blockIdx.x * SCAN_ITEMS + t * 4;
    int d[4]; int s = 0;
    #pragma unroll
    for (int k = 0; k < 4; ++k) {
        int idx = base + k;
        d[k] = (idx < NNODES) ? deg[idx] : 0;
        s += d[k];
    }
    lds[t] = s; __syncthreads();
    int v = s;
    for (int off = 1; off < 256; off <<= 1) {
        int add = (t >= off) ? lds[t - off] : 0;
        __syncthreads();
        lds[t] += add;
        __syncthreads();
    }
    int ex = lds[t] - v + bscan[blockIdx.x];
    #pragma unroll
    for (int k = 0; k < 4; ++k) {
        int idx = base + k;
        if (idx < NNODES) { rowptr[idx] = ex; ex += d[k]; }
    }
}

__global__ __launch_bounds__(256) void scatter_kernel(
    const int* __restrict__ rows, const int* __restrict__ cols,
    const float* __restrict__ vals, const int* __restrict__ rank,
    const int* __restrict__ rowptr, int2* __restrict__ edges)
{
    int e = blockIdx.x * 256 + threadIdx.x;
    if (e >= NEDGES) return;
    int pos = rowptr[rows[e]] + rank[e];
    edges[pos] = make_int2(cols[e], __float_as_int(vals[e]));
}

// ---------- weight fp32 -> bf16, TRANSPOSED to [layer][n][k] (once) ----------
__global__ __launch_bounds__(256) void wconv_kernel(
    const float* __restrict__ gw, const float* __restrict__ bw,
    unsigned short* __restrict__ wg_bf, unsigned short* __restrict__ wb_bf)
{
    int i = blockIdx.x * 256 + threadIdx.x;
    if (i >= NLAYERS * EMB * EMB) return;
    int l = i >> 12;
    int k = (i >> 6) & 63;
    int n = i & 63;
    int o = (l << 12) | (n << 6) | k;   // [l][n][k]
    wg_bf[o] = f2bf(gw[i]);
    wb_bf[o] = f2bf(bw[i]);
}

// ---------- ego init (bf16) + output cols 0..63 (fp32) ----------
__global__ __launch_bounds__(256) void init_kernel(
    const float* __restrict__ ue, const float* __restrict__ ie,
    unsigned short* __restrict__ ego_bf, float* __restrict__ out)
{
    int i = blockIdx.x * 256 + threadIdx.x;   // float4 index over NNODES*16
    if (i >= NNODES * 16) return;
    int n = i >> 4, q = i & 15;
    float4 v = (n < NUSERS) ? ((const float4*)ue)[i]
                            : ((const float4*)ie)[i - NUSERS * 16];
    *(float4*)(out + (size_t)n * 256 + q * 4) = v;
    ushort4 b;
    b.x = f2bf(v.x); b.y = f2bf(v.y); b.z = f2bf(v.z); b.w = f2bf(v.w);
    *(ushort4*)(ego_bf + (size_t)n * EMB + q * 4) = b;
}

// ---------- pull-mode SpMM v3: ONE ROW PER WAVE ----------
// r3 post-mortem: SpMM is gather-LATENCY bound (VALU work ~26us of ~100us).
// Wave = one row. Lane (cp=t&15, ke=(t>>4)&3): 4 edge slots x 16 col-lanes.
// Per iteration the wave gathers 4 edges' ego rows (4 x 128B) in one issue;
// x2 unroll = 8 gathers in flight. Dependent chain per row = deg/8 rounds
// (was deg/2 in r2) and zero intra-wave row imbalance. Epilogue: 2-level
// shfl_xor reduce over edge slots; lanes 0-15 store the row.
__global__ __launch_bounds__(256) void spmm_pull(
    const int* __restrict__ rowptr, const int2* __restrict__ edges,
    const unsigned short* __restrict__ ego_bf, unsigned short* __restrict__ side_bf)
{
    const int t  = threadIdx.x;
    const int cp = t & 15;                       // col chunk: cols cp*4..cp*4+3
    const int ke = (t >> 4) & 3;                 // edge slot within wave
    const int r  = __builtin_amdgcn_readfirstlane((int)blockIdx.x * 4 + (t >> 6));
    const int s = rowptr[r], e = rowptr[r + 1];

    float a0 = 0.f, a1 = 0.f, a2 = 0.f, a3 = 0.f;
    float b0 = 0.f, b1 = 0.f, b2 = 0.f, b3 = 0.f;
    int i = s;
    for (; i + 8 <= e; i += 8) {                 // 8 edges, 8 gathers in flight
        int2 e0 = edges[i + ke];
        int2 e1 = edges[i + 4 + ke];
        uint2 u0 = *(const uint2*)(ego_bf + (size_t)e0.x * EMB + cp * 4);
        uint2 u1 = *(const uint2*)(ego_bf + (size_t)e1.x * EMB + cp * 4);
        float v0 = __int_as_float(e0.y), v1 = __int_as_float(e1.y);
        a0 += v0 * bfl(u0.x); a1 += v0 * bfh(u0.x);
        a2 += v0 * bfl(u0.y); a3 += v0 * bfh(u0.y);
        b0 += v1 * bfl(u1.x); b1 += v1 * bfh(u1.x);
        b2 += v1 * bfl(u1.y); b3 += v1 * bfh(u1.y);
    }
    for (; i < e; i += 4) {                      // masked tail, 4 edges/round
        if (i + ke < e) {
            int2 e0 = edges[i + ke];
            uint2 u0 = *(const uint2*)(ego_bf + (size_t)e0.x * EMB + cp * 4);
            float v0 = __int_as_float(e0.y);
            a0 += v0 * bfl(u0.x); a1 += v0 * bfh(u0.x);
            a2 += v0 * bfl(u0.y); a3 += v0 * bfh(u0.y);
        }
    }
    a0 += b0; a1 += b1; a2 += b2; a3 += b3;

    // reduce across the 4 edge slots (lanes cp, cp+16, cp+32, cp+48)
    a0 += __shfl_xor(a0, 16, 64); a1 += __shfl_xor(a1, 16, 64);
    a2 += __shfl_xor(a2, 16, 64); a3 += __shfl_xor(a3, 16, 64);
    a0 += __shfl_xor(a0, 32, 64); a1 += __shfl_xor(a1, 32, 64);
    a2 += __shfl_xor(a2, 32, 64); a3 += __shfl_xor(a3, 32, 64);

    if (ke == 0) {
        ushort4 o;
        o.x = f2bf(a0); o.y = f2bf(a1); o.z = f2bf(a2); o.w = f2bf(a3);
        *(ushort4*)(side_bf + (size_t)r * EMB + cp * 4) = o;
    }
}

// ---------- MFMA dense: leaky(S@Wg+bg) + leaky((E*S)@Wb+bb), update ego, normalize ----------
// One wave per 16-row tile. 16x16x32 bf16 MFMA:
//   A[m=lane&15][k=(lane>>4)*8+j]; C/D: col=lane&15, row=(lane>>4)*4+reg.
// Weights arrive TRANSPOSED [n][k]: B-fragment = contiguous short8 load.
// NOTE r3: fusing this with SpMM via LDS regressed (barrier-coupled degree
// imbalance, occupancy 33%) — keep separate dispatches.
__global__ __launch_bounds__(256) void dense_mfma(
    const unsigned short* __restrict__ side_bf, unsigned short* __restrict__ ego_bf,
    const unsigned short* __restrict__ wg_bf, const unsigned short* __restrict__ wb_bf,
    const float* __restrict__ gb, const float* __restrict__ bb,
    float* __restrict__ out, int out_col0)
{
    const int lane = threadIdx.x & 63;
    const int w    = threadIdx.x >> 6;
    const int m    = lane & 15;     // row (A) / col (B, C)
    const int q    = lane >> 4;     // quad

    const int t = (int)blockIdx.x * 4 + w;     // 16-row tile index
    if (t >= NTILES) return;

    // ---- B fragments: [n0][kh], lane j holds B[k=kh*32+q*8+j][n=n0*16+m]
    short8 bg[4][2], bbf[4][2];
    #pragma unroll
    for (int n0 = 0; n0 < 4; ++n0) {
        const int n = n0 * 16 + m;
        #pragma unroll
        for (int kh = 0; kh < 2; ++kh) {
            bg [n0][kh] = *(const short8*)(wg_bf + n * EMB + kh * 32 + q * 8);
            bbf[n0][kh] = *(const short8*)(wb_bf + n * EMB + kh * 32 + q * 8);
        }
    }
    float bgc[4], bbc[4];
    #pragma unroll
    for (int n0 = 0; n0 < 4; ++n0) { bgc[n0] = gb[n0 * 16 + m]; bbc[n0] = bb[n0 * 16 + m]; }

    // ---- A fragments: rows t*16 .. t*16+15
    const size_t base = (size_t)t * 16 * EMB;
    const int ao = m * EMB + q * 8;
    short8 as0 = *(const short8*)(side_bf + base + ao);
    short8 as1 = *(const short8*)(side_bf + base + ao + 32);
    short8 ae0 = *(const short8*)(ego_bf  + base + ao);
    short8 ae1 = *(const short8*)(ego_bf  + base + ao + 32);
    short8 ap0, ap1;
    #pragma unroll
    for (int jj = 0; jj < 8; ++jj) {
        ap0[jj] = (short)f2bf(bf2f((unsigned short)as0[jj]) * bf2f((unsigned short)ae0[jj]));
        ap1[jj] = (short)f2bf(bf2f((unsigned short)as1[jj]) * bf2f((unsigned short)ae1[jj]));
    }

    // ---- MFMAs
    float4v c1[4], c2[4];
    #pragma unroll
    for (int n0 = 0; n0 < 4; ++n0) { c1[n0] = (float4v)0.f; c2[n0] = (float4v)0.f; }
    #pragma unroll
    for (int n0 = 0; n0 < 4; ++n0) {
        c1[n0] = __builtin_amdgcn_mfma_f32_16x16x32_bf16(as0, bg [n0][0], c1[n0], 0, 0, 0);
        c1[n0] = __builtin_amdgcn_mfma_f32_16x16x32_bf16(as1, bg [n0][1], c1[n0], 0, 0, 0);
        c2[n0] = __builtin_amdgcn_mfma_f32_16x16x32_bf16(ap0, bbf[n0][0], c2[n0], 0, 0, 0);
        c2[n0] = __builtin_amdgcn_mfma_f32_16x16x32_bf16(ap1, bbf[n0][1], c2[n0], 0, 0, 0);
    }

    // ---- epilogue: bias + leaky + ego update + L2 norm
    float eg[4][4];          // [n0][reg]; row = t*16 + q*4 + reg, col = n0*16 + m
    float ss[4] = {0.f, 0.f, 0.f, 0.f};
    #pragma unroll
    for (int n0 = 0; n0 < 4; ++n0) {
        #pragma unroll
        for (int r = 0; r < 4; ++r) {
            float x1 = c1[n0][r] + bgc[n0];
            float x2 = c2[n0][r] + bbc[n0];
            float v1 = x1 > 0.f ? x1 : 0.01f * x1;
            float v2 = x2 > 0.f ? x2 : 0.01f * x2;
            float e = v1 + v2;
            eg[n0][r] = e;
            ss[r] += e * e;
        }
    }
    #pragma unroll
    for (int r = 0; r < 4; ++r) {
        float s = ss[r];
        s += __shfl_xor(s, 1, 64);
        s += __shfl_xor(s, 2, 64);
        s += __shfl_xor(s, 4, 64);
        s += __shfl_xor(s, 8, 64);
        ss[r] = 1.0f / fmaxf(sqrtf(s), 1e-12f);
    }
    #pragma unroll
    for (int r = 0; r < 4; ++r) {
        int row = t * 16 + q * 4 + r;
        #pragma unroll
        for (int n0 = 0; n0 < 4; ++n0) {
            int col = n0 * 16 + m;
            ego_bf[(size_t)row * EMB + col] = f2bf(eg[n0][r]);
            out[(size_t)row * 256 + out_col0 + col] = eg[n0][r] * ss[r];
        }
    }
}

extern "C" void kernel_launch(void* const* d_in, const int* in_sizes, int n_in,
                              void* d_out, int out_size, void* d_ws, size_t ws_size,
                              hipStream_t stream)
{
    const int*   rows = (const int*)  d_in[0];
    const int*   cols = (const int*)  d_in[1];
    const float* vals = (const float*)d_in[2];
    const float* ue   = (const float*)d_in[3];
    const float* ie   = (const float*)d_in[4];
    const float* gw   = (const float*)d_in[5];
    const float* gb   = (const float*)d_in[6];
    const float* bw   = (const float*)d_in[7];
    const float* bb   = (const float*)d_in[8];
    float* out = (float*)d_out;

    // ---- workspace layout (~58.3 MB) ----
    char* p = (char*)d_ws;
    unsigned short* ego_bf  = (unsigned short*)p;  p += (size_t)NNODES * EMB * 2;  // 19.2 MB
    unsigned short* side_bf = (unsigned short*)p;  p += (size_t)NNODES * EMB * 2;  // 19.2 MB
    int2*  edges  = (int2*)p;    p += (size_t)NEDGES * 8;                          // 19.2 MB
    int*   rowptr = (int*)p;     p += ((size_t)NNODES + 4) * 4;                    // 0.6 MB
    unsigned short* wg_bf = (unsigned short*)p;  p += (size_t)NLAYERS * EMB * EMB * 2;
    unsigned short* wb_bf = (unsigned short*)p;  p += (size_t)NLAYERS * EMB * EMB * 2;
    // build scratch aliased into side region (10.2 MB < 19.2 MB; side rewritten each layer)
    int* deg   = (int*)side_bf;
    int* rank  = (int*)side_bf + NNODES;
    int* bsum  = (int*)side_bf + NNODES + NEDGES;
    int* bscan = bsum + 256;

    // ---- CSR build ----
    hipMemsetAsync(deg, 0, (size_t)NNODES * 4, stream);
    hist_rank_kernel<<<(NEDGES + 255) / 256, 256, 0, stream>>>(rows, deg, rank);
    block_sum_kernel<<<NSCAN_BLOCKS, 256, 0, stream>>>(deg, bsum);
    scan_partials_kernel<<<1, 256, 0, stream>>>(bsum, bscan, rowptr);
    block_scan_kernel<<<NSCAN_BLOCKS, 256, 0, stream>>>(deg, bscan, rowptr);
    scatter_kernel<<<(NEDGES + 255) / 256, 256, 0, stream>>>(
        rows, cols, vals, rank, rowptr, edges);

    wconv_kernel<<<(NLAYERS * EMB * EMB + 255) / 256, 256, 0, stream>>>(gw, bw, wg_bf, wb_bf);
    init_kernel<<<(NNODES * 16 + 255) / 256, 256, 0, stream>>>(ue, ie, ego_bf, out);

    for (int l = 0; l < NLAYERS; ++l) {
        spmm_pull<<<NNODES / 4, 256, 0, stream>>>(rowptr, edges, ego_bf, side_bf);
        dense_mfma<<<(NTILES + 3) / 4, 256, 0, stream>>>(
            side_bf, ego_bf,
            wg_bf + l * EMB * EMB, wb_bf + l * EMB * EMB,
            gb + l * EMB, bb + l * EMB,
            out, 64 * (l + 1));
    }
}

// Round 5
// 616.330 us; speedup vs baseline: 1.1166x; 1.0674x over previous
//
#include <hip/hip_runtime.h>
#include <hip/hip_bf16.h>

#define NUSERS 100000
#define NITEMS 50000
#define NNODES 150000
#define EMB 64
#define NLAYERS 3
#define NEDGES 2400000
#define NTILES (NNODES / 16)                                    // 9375
#define NB 293          // buckets of 512 rows: (150000+511)/512
#define EPB (NEDGES / 256)   // 9375 edges per block in stages A/C

typedef __attribute__((ext_vector_type(8))) short short8;
typedef __attribute__((ext_vector_type(4))) float float4v;

__device__ __forceinline__ float bf2f(unsigned short u) {
    return __uint_as_float((unsigned int)u << 16);
}
__device__ __forceinline__ unsigned short f2bf(float f) {
    unsigned int x = __float_as_uint(f);
    return (unsigned short)((x + 0x7FFFu + ((x >> 16) & 1u)) >> 16);   // RNE
}
__device__ __forceinline__ float bfl(unsigned int u) { return __uint_as_float(u << 16); }
__device__ __forceinline__ float bfh(unsigned int u) { return __uint_as_float(u & 0xffff0000u); }

// ---------- CSR build via LDS-only counting sort ----------
// MEASURED HISTORY (do not re-try):
//  - r0/r4: global-atomic hist_rank = 101-106us. WRITE_SIZE 86MB = 2.4M x 36B:
//    every device-scope atomic write-throughs to HBM as its own ~32B granule
//    (deg[] is 600KB; write-combining would give 0.6MB). HBM random-write wall.
//  - r3: 8-way issuer-side privatization (bucket=blockIdx&7) REGRESSED +56us.
//    Atomics execute at the address-home slice; issuer bucketing is a no-op.
//  => r5: counting sort by 512-row bucket, ALL atomics in LDS, zero global.

// Stage A: per-block LDS histogram over NB buckets -> cnt[bucket*256+block]
__global__ __launch_bounds__(256) void bucket_count_kernel(
    const int* __restrict__ rows, int* __restrict__ cnt)
{
    __shared__ int hist[NB];
    const int t = threadIdx.x, blk = blockIdx.x;
    for (int i = t; i < NB; i += 256) hist[i] = 0;
    __syncthreads();
    const int base = blk * EPB;
    for (int i = t; i < EPB; i += 256)
        atomicAdd(&hist[rows[base + i] >> 9], 1);
    __syncthreads();
    for (int i = t; i < NB; i += 256) cnt[i * 256 + blk] = hist[i];
}

// Stage B: single-block exclusive scan of cnt[NB*256] (bucket-major), in place.
__global__ __launch_bounds__(256) void bucket_scan_kernel(int* __restrict__ cnt)
{
    __shared__ int part[256];
    const int t = threadIdx.x;
    const int lo = t * NB;              // 256 threads x NB elems = NB*256 total
    int s = 0;
    for (int i = 0; i < NB; ++i) s += cnt[lo + i];
    part[t] = s; __syncthreads();
    int v = s;
    for (int off = 1; off < 256; off <<= 1) {
        int add = (t >= off) ? part[t - off] : 0;
        __syncthreads();
        part[t] += add;
        __syncthreads();
    }
    int run = part[t] - v;              // exclusive prefix of this chunk
    for (int i = 0; i < NB; ++i) {
        int c = cnt[lo + i];
        cnt[lo + i] = run;
        run += c;
    }
}

// Stage C: scatter edges into bucket-major staging; pack lrow(9b)<<18 | col(18b).
__global__ __launch_bounds__(256) void bucket_scatter_kernel(
    const int* __restrict__ rows, const int* __restrict__ cols,
    const float* __restrict__ vals, const int* __restrict__ offs,
    int2* __restrict__ staged)
{
    __shared__ int cur[NB];
    const int t = threadIdx.x, blk = blockIdx.x;
    for (int i = t; i < NB; i += 256) cur[i] = offs[i * 256 + blk];
    __syncthreads();
    const int base = blk * EPB;
    for (int i = t; i < EPB; i += 256) {
        int e = base + i;
        int r = rows[e];
        int pos = atomicAdd(&cur[r >> 9], 1);
        staged[pos] = make_int2(((r & 511) << 18) | cols[e], __float_as_int(vals[e]));
    }
}

// Stage D: one block per bucket. LDS deg/scan/cursor over 512 local rows ->
// final row-sorted edges + rowptr. (Order within a row unstable: sum-only use.)
__global__ __launch_bounds__(256) void bucket_csr_kernel(
    const int* __restrict__ offs, const int2* __restrict__ staged,
    int* __restrict__ rowptr, int2* __restrict__ edges)
{
    __shared__ int deg[512];
    __shared__ int cur[512];
    __shared__ int part[256];
    const int t = threadIdx.x, b = blockIdx.x;
    const int bstart = offs[b * 256];
    const int bend   = (b + 1 < NB) ? offs[(b + 1) * 256] : NEDGES;
    deg[t] = 0; deg[t + 256] = 0;
    __syncthreads();
    for (int i = bstart + t; i < bend; i += 256)
        atomicAdd(&deg[staged[i].x >> 18], 1);
    __syncthreads();
    // exclusive scan over 512 (2 elems/thread)
    int d0 = deg[2 * t], d1 = deg[2 * t + 1];
    int s = d0 + d1;
    part[t] = s; __syncthreads();
    int v = s;
    for (int off = 1; off < 256; off <<= 1) {
        int add = (t >= off) ? part[t - off] : 0;
        __syncthreads();
        part[t] += add;
        __syncthreads();
    }
    int ex = part[t] - v;
    cur[2 * t]     = ex;
    cur[2 * t + 1] = ex + d0;
    int grow = b * 512 + 2 * t;
    if (grow < NNODES)     rowptr[grow]     = bstart + ex;
    if (grow + 1 < NNODES) rowptr[grow + 1] = bstart + ex + d0;
    if (b == 0 && t == 0)  rowptr[NNODES] = NEDGES;
    __syncthreads();
    for (int i = bstart + t; i < bend; i += 256) {
        int2 se = staged[i];
        int pos = atomicAdd(&cur[se.x >> 18], 1);
        edges[bstart + pos] = make_int2(se.x & 0x3FFFF, se.y);
    }
}

// ---------- weight fp32 -> bf16, TRANSPOSED to [layer][n][k] (once) ----------
__global__ __launch_bounds__(256) void wconv_kernel(
    const float* __restrict__ gw, const float* __restrict__ bw,
    unsigned short* __restrict__ wg_bf, unsigned short* __restrict__ wb_bf)
{
    int i = blockIdx.x * 256 + threadIdx.x;
    if (i >= NLAYERS * EMB * EMB) return;
    int l = i >> 12;
    int k = (i >> 6) & 63;
    int n = i & 63;
    int o = (l << 12) | (n << 6) | k;   // [l][n][k]
    wg_bf[o] = f2bf(gw[i]);
    wb_bf[o] = f2bf(bw[i]);
}

// ---------- ego init (bf16) + output cols 0..63 (fp32) ----------
__global__ __launch_bounds__(256) void init_kernel(
    const float* __restrict__ ue, const float* __restrict__ ie,
    unsigned short* __restrict__ ego_bf, float* __restrict__ out)
{
    int i = blockIdx.x * 256 + threadIdx.x;   // float4 index over NNODES*16
    if (i >= NNODES * 16) return;
    int n = i >> 4, q = i & 15;
    float4 v = (n < NUSERS) ? ((const float4*)ue)[i]
                            : ((const float4*)ie)[i - NUSERS * 16];
    *(float4*)(out + (size_t)n * 256 + q * 4) = v;
    ushort4 b;
    b.x = f2bf(v.x); b.y = f2bf(v.y); b.z = f2bf(v.z); b.w = f2bf(v.w);
    *(ushort4*)(ego_bf + (size_t)n * EMB + q * 4) = b;
}

// ---------- pull-mode SpMM v2 (measured best, r2=632us config) ----------
// One row per 16-lane group; lane cp owns cols cp*4..cp*4+3 (uint2 gather).
// r4 measured: one-row-per-wave with shfl-reduce (v3) was ~9us/layer WORSE.
__global__ __launch_bounds__(256) void spmm_pull(
    const int* __restrict__ rowptr, const int2* __restrict__ edges,
    const unsigned short* __restrict__ ego_bf, unsigned short* __restrict__ side_bf)
{
    const int t  = threadIdx.x;
    const int cp = t & 15;                       // col-chunk: cols cp*4..cp*4+3
    const int r  = blockIdx.x * 16 + (t >> 4);   // 16 rows/block, 4/wave
    const int s = rowptr[r], e = rowptr[r + 1];

    float a0 = 0.f, a1 = 0.f, a2 = 0.f, a3 = 0.f;
    float b0 = 0.f, b1 = 0.f, b2 = 0.f, b3 = 0.f;
    int i = s;
    for (; i + 2 <= e; i += 2) {                 // 2 edges in flight (4 loads)
        int2 e0 = edges[i];
        int2 e1 = edges[i + 1];
        float v0 = __int_as_float(e0.y);
        float v1 = __int_as_float(e1.y);
        uint2 u0 = *(const uint2*)(ego_bf + (size_t)e0.x * EMB + cp * 4);
        uint2 u1 = *(const uint2*)(ego_bf + (size_t)e1.x * EMB + cp * 4);
        a0 += v0 * bfl(u0.x); a1 += v0 * bfh(u0.x);
        a2 += v0 * bfl(u0.y); a3 += v0 * bfh(u0.y);
        b0 += v1 * bfl(u1.x); b1 += v1 * bfh(u1.x);
        b2 += v1 * bfl(u1.y); b3 += v1 * bfh(u1.y);
    }
    if (i < e) {
        int2 e0 = edges[i];
        float v0 = __int_as_float(e0.y);
        uint2 u0 = *(const uint2*)(ego_bf + (size_t)e0.x * EMB + cp * 4);
        a0 += v0 * bfl(u0.x); a1 += v0 * bfh(u0.x);
        a2 += v0 * bfl(u0.y); a3 += v0 * bfh(u0.y);
    }
    a0 += b0; a1 += b1; a2 += b2; a3 += b3;

    ushort4 o;
    o.x = f2bf(a0); o.y = f2bf(a1); o.z = f2bf(a2); o.w = f2bf(a3);
    *(ushort4*)(side_bf + (size_t)r * EMB + cp * 4) = o;
}

// ---------- MFMA dense: leaky(S@Wg+bg) + leaky((E*S)@Wb+bb), update ego, normalize ----------
// One wave per 16-row tile. 16x16x32 bf16 MFMA:
//   A[m=lane&15][k=(lane>>4)*8+j]; C/D: col=lane&15, row=(lane>>4)*4+reg.
// Weights arrive TRANSPOSED [n][k]: B-fragment = contiguous short8 load.
// NOTE r3: fusing this with SpMM via LDS regressed (barrier-coupled degree
// imbalance, occupancy 33%) — keep separate dispatches.
__global__ __launch_bounds__(256) void dense_mfma(
    const unsigned short* __restrict__ side_bf, unsigned short* __restrict__ ego_bf,
    const unsigned short* __restrict__ wg_bf, const unsigned short* __restrict__ wb_bf,
    const float* __restrict__ gb, const float* __restrict__ bb,
    float* __restrict__ out, int out_col0)
{
    const int lane = threadIdx.x & 63;
    const int w    = threadIdx.x >> 6;
    const int m    = lane & 15;     // row (A) / col (B, C)
    const int q    = lane >> 4;     // quad

    const int t = (int)blockIdx.x * 4 + w;     // 16-row tile index
    if (t >= NTILES) return;

    // ---- B fragments: [n0][kh], lane j holds B[k=kh*32+q*8+j][n=n0*16+m]
    short8 bg[4][2], bbf[4][2];
    #pragma unroll
    for (int n0 = 0; n0 < 4; ++n0) {
        const int n = n0 * 16 + m;
        #pragma unroll
        for (int kh = 0; kh < 2; ++kh) {
            bg [n0][kh] = *(const short8*)(wg_bf + n * EMB + kh * 32 + q * 8);
            bbf[n0][kh] = *(const short8*)(wb_bf + n * EMB + kh * 32 + q * 8);
        }
    }
    float bgc[4], bbc[4];
    #pragma unroll
    for (int n0 = 0; n0 < 4; ++n0) { bgc[n0] = gb[n0 * 16 + m]; bbc[n0] = bb[n0 * 16 + m]; }

    // ---- A fragments: rows t*16 .. t*16+15
    const size_t base = (size_t)t * 16 * EMB;
    const int ao = m * EMB + q * 8;
    short8 as0 = *(const short8*)(side_bf + base + ao);
    short8 as1 = *(const short8*)(side_bf + base + ao + 32);
    short8 ae0 = *(const short8*)(ego_bf  + base + ao);
    short8 ae1 = *(const short8*)(ego_bf  + base + ao + 32);
    short8 ap0, ap1;
    #pragma unroll
    for (int jj = 0; jj < 8; ++jj) {
        ap0[jj] = (short)f2bf(bf2f((unsigned short)as0[jj]) * bf2f((unsigned short)ae0[jj]));
        ap1[jj] = (short)f2bf(bf2f((unsigned short)as1[jj]) * bf2f((unsigned short)ae1[jj]));
    }

    // ---- MFMAs
    float4v c1[4], c2[4];
    #pragma unroll
    for (int n0 = 0; n0 < 4; ++n0) { c1[n0] = (float4v)0.f; c2[n0] = (float4v)0.f; }
    #pragma unroll
    for (int n0 = 0; n0 < 4; ++n0) {
        c1[n0] = __builtin_amdgcn_mfma_f32_16x16x32_bf16(as0, bg [n0][0], c1[n0], 0, 0, 0);
        c1[n0] = __builtin_amdgcn_mfma_f32_16x16x32_bf16(as1, bg [n0][1], c1[n0], 0, 0, 0);
        c2[n0] = __builtin_amdgcn_mfma_f32_16x16x32_bf16(ap0, bbf[n0][0], c2[n0], 0, 0, 0);
        c2[n0] = __builtin_amdgcn_mfma_f32_16x16x32_bf16(ap1, bbf[n0][1], c2[n0], 0, 0, 0);
    }

    // ---- epilogue: bias + leaky + ego update + L2 norm
    float eg[4][4];          // [n0][reg]; row = t*16 + q*4 + reg, col = n0*16 + m
    float ss[4] = {0.f, 0.f, 0.f, 0.f};
    #pragma unroll
    for (int n0 = 0; n0 < 4; ++n0) {
        #pragma unroll
        for (int r = 0; r < 4; ++r) {
            float x1 = c1[n0][r] + bgc[n0];
            float x2 = c2[n0][r] + bbc[n0];
            float v1 = x1 > 0.f ? x1 : 0.01f * x1;
            float v2 = x2 > 0.f ? x2 : 0.01f * x2;
            float e = v1 + v2;
            eg[n0][r] = e;
            ss[r] += e * e;
        }
    }
    #pragma unroll
    for (int r = 0; r < 4; ++r) {
        float s = ss[r];
        s += __shfl_xor(s, 1, 64);
        s += __shfl_xor(s, 2, 64);
        s += __shfl_xor(s, 4, 64);
        s += __shfl_xor(s, 8, 64);
        ss[r] = 1.0f / fmaxf(sqrtf(s), 1e-12f);
    }
    #pragma unroll
    for (int r = 0; r < 4; ++r) {
        int row = t * 16 + q * 4 + r;
        #pragma unroll
        for (int n0 = 0; n0 < 4; ++n0) {
            int col = n0 * 16 + m;
            ego_bf[(size_t)row * EMB + col] = f2bf(eg[n0][r]);
            out[(size_t)row * 256 + out_col0 + col] = eg[n0][r] * ss[r];
        }
    }
}

extern "C" void kernel_launch(void* const* d_in, const int* in_sizes, int n_in,
                              void* d_out, int out_size, void* d_ws, size_t ws_size,
                              hipStream_t stream)
{
    const int*   rows = (const int*)  d_in[0];
    const int*   cols = (const int*)  d_in[1];
    const float* vals = (const float*)d_in[2];
    const float* ue   = (const float*)d_in[3];
    const float* ie   = (const float*)d_in[4];
    const float* gw   = (const float*)d_in[5];
    const float* gb   = (const float*)d_in[6];
    const float* bw   = (const float*)d_in[7];
    const float* bb   = (const float*)d_in[8];
    float* out = (float*)d_out;

    // ---- workspace layout (~58.6 MB) ----
    char* p = (char*)d_ws;
    unsigned short* ego_bf  = (unsigned short*)p;  p += (size_t)NNODES * EMB * 2;  // 19.2 MB
    unsigned short* side_bf = (unsigned short*)p;  p += (size_t)NNODES * EMB * 2;  // 19.2 MB
    int2*  edges  = (int2*)p;    p += (size_t)NEDGES * 8;                          // 19.2 MB
    int*   rowptr = (int*)p;     p += ((size_t)NNODES + 4) * 4;                    // 0.6 MB
    unsigned short* wg_bf = (unsigned short*)p;  p += (size_t)NLAYERS * EMB * EMB * 2;
    unsigned short* wb_bf = (unsigned short*)p;  p += (size_t)NLAYERS * EMB * EMB * 2;
    int*   cnt    = (int*)p;     p += (size_t)NB * 256 * 4;                        // 0.3 MB
    // bucket-major staging aliased into side region (19.2 MB == NEDGES*8 exactly;
    // side_bf is first written by layer-0 spmm, after the build completes)
    int2* staged = (int2*)side_bf;

    // ---- CSR build: LDS-only counting sort (no global atomics) ----
    bucket_count_kernel  <<<256, 256, 0, stream>>>(rows, cnt);
    bucket_scan_kernel   <<<1,   256, 0, stream>>>(cnt);
    bucket_scatter_kernel<<<256, 256, 0, stream>>>(rows, cols, vals, cnt, staged);
    bucket_csr_kernel    <<<NB,  256, 0, stream>>>(cnt, staged, rowptr, edges);

    wconv_kernel<<<(NLAYERS * EMB * EMB + 255) / 256, 256, 0, stream>>>(gw, bw, wg_bf, wb_bf);
    init_kernel<<<(NNODES * 16 + 255) / 256, 256, 0, stream>>>(ue, ie, ego_bf, out);

    for (int l = 0; l < NLAYERS; ++l) {
        spmm_pull<<<NNODES / 16, 256, 0, stream>>>(rowptr, edges, ego_bf, side_bf);
        dense_mfma<<<(NTILES + 3) / 4, 256, 0, stream>>>(
            side_bf, ego_bf,
            wg_bf + l * EMB * EMB, wb_bf + l * EMB * EMB,
            gb + l * EMB, bb + l * EMB,
            out, 64 * (l + 1));
    }
}